// Round 11
// baseline (68.824 us; speedup 1.0000x reference)
//
#include <hip/hip_runtime.h>
#include <cstdint>

#define B8   8
#define DIN  1024
#define NH1  2048
#define NH2  1024
#define NOUT 5120
#define TKS  5      // tropical k-split (5120 = 5 * 1024)

__device__ __forceinline__ float4 ld4(const float* p) {
  return *reinterpret_cast<const float4*>(p);
}
__device__ __forceinline__ void st4(float* p, float4 v) {
  *reinterpret_cast<float4*>(p) = v;
}

// C_parts[kb][8][N] = A[8, k0:k0+KC] @ W[k0:k0+KC, :]   (partial over K-chunk)
// A source: raw input (NPART==0) or sum of NPART partials + bias (+ReLU).
// The staged (finalized) A chunk is optionally written out (features).
template<int K, int N, int KSPLIT, int NPART, bool RELU_IN, bool WRITE_STAGE>
__global__ __launch_bounds__(256)
void gemm8(const float* __restrict__ Asrc, const float* __restrict__ bias_in,
           const float* __restrict__ W, float* __restrict__ Cparts,
           float* __restrict__ stage_out)
{
  constexpr int KC    = K / KSPLIT;   // k-chunk per block
  constexpr int KC4   = KC / 4;
  constexpr int NCOLB = N / 64;       // 64 output cols per block
  constexpr int KT    = KC / 16;      // k elements per thread

  __shared__ float A_lds[8][KC];      // <= 8 KB
  __shared__ float red[16][8][64];    // 32 KB

  const int tid = threadIdx.x;
  const int kb  = blockIdx.x / NCOLB;
  const int cb  = blockIdx.x % NCOLB;
  const int k0  = kb * KC;

  // ---- stage A chunk into LDS (finalize previous stage: sum partials + bias + relu)
  for (int e = tid; e < 8 * KC4; e += 256) {
    const int b = e / KC4, k4 = e - b * KC4;
    float4 v;
    if constexpr (NPART == 0) {
      v = ld4(&Asrc[(size_t)b * K + k0 + 4 * k4]);
    } else {
      v = ld4(&bias_in[k0 + 4 * k4]);
      #pragma unroll
      for (int p = 0; p < NPART; ++p) {
        float4 t = ld4(&Asrc[((size_t)p * 8 + b) * K + k0 + 4 * k4]);
        v.x += t.x; v.y += t.y; v.z += t.z; v.w += t.w;
      }
      if constexpr (RELU_IN) {
        v.x = fmaxf(v.x, 0.f); v.y = fmaxf(v.y, 0.f);
        v.z = fmaxf(v.z, 0.f); v.w = fmaxf(v.w, 0.f);
      }
    }
    st4(&A_lds[b][4 * k4], v);
    if constexpr (WRITE_STAGE) {
      if (cb == 0) st4(&stage_out[(size_t)b * K + k0 + 4 * k4], v);
    }
  }
  __syncthreads();

  // ---- main loop: 16 col-groups (float4) x 16 k-slices
  const int g  = tid & 15, ks = tid >> 4;
  const int c0 = cb * 64 + g * 4;
  float4 acc[8];
  #pragma unroll
  for (int b = 0; b < 8; ++b) acc[b] = make_float4(0.f, 0.f, 0.f, 0.f);

  const float* Wp = &W[(size_t)(k0 + ks * KT) * N + c0];
  #pragma unroll
  for (int i = 0; i < KT; i += 4) {
    const float4 w0 = ld4(Wp + (size_t)(i + 0) * N);
    const float4 w1 = ld4(Wp + (size_t)(i + 1) * N);
    const float4 w2 = ld4(Wp + (size_t)(i + 2) * N);
    const float4 w3 = ld4(Wp + (size_t)(i + 3) * N);
    const int kk = ks * KT + i;
    #pragma unroll
    for (int b = 0; b < 8; ++b) {
      const float4 a = ld4(&A_lds[b][kk]);   // broadcast within 16-lane group
      acc[b].x += a.x * w0.x + a.y * w1.x + a.z * w2.x + a.w * w3.x;
      acc[b].y += a.x * w0.y + a.y * w1.y + a.z * w2.y + a.w * w3.y;
      acc[b].z += a.x * w0.z + a.y * w1.z + a.z * w2.z + a.w * w3.z;
      acc[b].w += a.x * w0.w + a.y * w1.w + a.z * w2.w + a.w * w3.w;
    }
  }

  // ---- reduce the 16 k-slices through LDS
  __syncthreads();
  #pragma unroll
  for (int b = 0; b < 8; ++b) st4(&red[ks][b][g * 4], acc[b]);
  __syncthreads();

  for (int p = tid; p < 512; p += 256) {
    const int c = p & 63, b = p >> 6;
    float s = 0.f;
    #pragma unroll
    for (int j = 0; j < 16; ++j) s += red[j][b][c];
    Cparts[((size_t)kb * 8 + b) * N + cb * 64 + c] = s;
  }
}

// logits[8][5120] = sum of 4 partials + b3
__global__ __launch_bounds__(256)
void finalize_logits(const float* __restrict__ parts, const float* __restrict__ b3,
                     float* __restrict__ logits)
{
  const int i  = blockIdx.x * 256 + threadIdx.x;   // 10240 float4s, grid exact
  const int b  = i / 1280, k4 = i - b * 1280;
  float4 v = ld4(&b3[4 * k4]);
  #pragma unroll
  for (int p = 0; p < 4; ++p) {
    const float4 t = ld4(&parts[((size_t)p * 8 + b) * NOUT + 4 * k4]);
    v.x += t.x; v.y += t.y; v.z += t.z; v.w += t.w;
  }
  st4(&logits[(size_t)b * NOUT + 4 * k4], v);
}

// tpart[ks][b][o] = max_{k in chunk ks} logits[b][k] * CM[o][k]
// LOGITS-IN-REGISTERS: each wave holds an entire [8 b][1024 k] logits window
// in VGPRs (lg[8][4] float4, loaded ONCE, coalesced) and walks 16 CM rows
// with it. Kills the 3-5x logits re-read amplification that capped every
// previous variant at the per-CU ingest ceiling (~20-25 B/cyc/CU). Per row:
// 4 coalesced CM loads + 512 cyc of independent VALU; A/B row ping-pong
// with NAMED buffers (static indices). No LDS, no barriers, ~190 VGPR.
__global__ __launch_bounds__(256)
void tropical_reg(const float* __restrict__ logits, const float* __restrict__ CM,
                  float* __restrict__ tpart)
{
  const int tid = threadIdx.x;
  const int w   = tid >> 6;      // wave 0..3
  const int l   = tid & 63;      // lane
  const int ks  = blockIdx.y;    // k-chunk 0..4
  const int k0  = ks * 1024;
  const int o0  = (blockIdx.x * 4 + w) * 16;   // wave's 16 rows
  const int kb  = k0 + 4 * l;                  // lane's k base (quad j at +256j)

  // ---- logits window into registers (32 coalesced 1KB wave-loads, once)
  float4 lg[8][4];
  #pragma unroll
  for (int b = 0; b < 8; ++b)
    #pragma unroll
    for (int j = 0; j < 4; ++j)
      lg[b][j] = ld4(&logits[(size_t)b * NOUT + kb + 256 * j]);

  const float* cmA = &CM[(size_t)o0 * NOUT + kb];        // row being computed (A)
  const float* cmB = cmA + NOUT;                         // row B

  float4 cA[4], cB[4];
  #pragma unroll
  for (int j = 0; j < 4; ++j) cA[j] = ld4(cmA + 256 * j);
  #pragma unroll
  for (int j = 0; j < 4; ++j) cB[j] = ld4(cmB + 256 * j);

  float* tp = &tpart[(size_t)ks * 8 * NOUT];

  for (int p = 0; p < 8; ++p) {          // 8 row-pairs, rolled (static bufs)
    // ---- row 2p from cA
    float pm[8];
    #pragma unroll
    for (int b = 0; b < 8; ++b) pm[b] = -3.402823466e38f;
    #pragma unroll
    for (int j = 0; j < 4; ++j) {
      const float4 C = cA[j];
      #pragma unroll
      for (int b = 0; b < 8; ++b) {
        const float4 lv = lg[b][j];
        const float m0 = fmaxf(lv.x * C.x, lv.y * C.y);
        const float m1 = fmaxf(lv.z * C.z, lv.w * C.w);
        pm[b] = fmaxf(pm[b], fmaxf(m0, m1));
      }
    }
    cmA += 2 * NOUT;                     // refill A for row 2p+2 (in flight
    if (p < 7) {                         // under row 2p+1's compute)
      #pragma unroll
      for (int j = 0; j < 4; ++j) cA[j] = ld4(cmA + 256 * j);
    }
    #pragma unroll
    for (int b = 0; b < 8; ++b) {
      float v = pm[b];
      for (int m = 32; m; m >>= 1) v = fmaxf(v, __shfl_xor(v, m));
      if (l == 0) tp[(size_t)b * NOUT + o0 + 2 * p] = v;
    }

    // ---- row 2p+1 from cB
    float pn[8];
    #pragma unroll
    for (int b = 0; b < 8; ++b) pn[b] = -3.402823466e38f;
    #pragma unroll
    for (int j = 0; j < 4; ++j) {
      const float4 C = cB[j];
      #pragma unroll
      for (int b = 0; b < 8; ++b) {
        const float4 lv = lg[b][j];
        const float m0 = fmaxf(lv.x * C.x, lv.y * C.y);
        const float m1 = fmaxf(lv.z * C.z, lv.w * C.w);
        pn[b] = fmaxf(pn[b], fmaxf(m0, m1));
      }
    }
    cmB += 2 * NOUT;                     // refill B for row 2p+3
    if (p < 7) {
      #pragma unroll
      for (int j = 0; j < 4; ++j) cB[j] = ld4(cmB + 256 * j);
    }
    #pragma unroll
    for (int b = 0; b < 8; ++b) {
      float v = pn[b];
      for (int m = 32; m; m >>= 1) v = fmaxf(v, __shfl_xor(v, m));
      if (l == 0) tp[(size_t)b * NOUT + o0 + 2 * p + 1] = v;
    }
  }
}

// out[b][o] = max_ks tpart[ks][b][o]
__global__ __launch_bounds__(256)
void tropical_combine(const float* __restrict__ tpart, float* __restrict__ out)
{
  const int i = blockIdx.x * 256 + threadIdx.x;   // 10240 float4s, grid exact
  float4 v = ld4(&tpart[4 * (size_t)i]);
  #pragma unroll
  for (int p = 1; p < TKS; ++p) {
    const float4 t = ld4(&tpart[(size_t)p * 8 * NOUT + 4 * (size_t)i]);
    v.x = fmaxf(v.x, t.x); v.y = fmaxf(v.y, t.y);
    v.z = fmaxf(v.z, t.z); v.w = fmaxf(v.w, t.w);
  }
  st4(&out[4 * (size_t)i], v);
}

extern "C" void kernel_launch(void* const* d_in, const int* in_sizes, int n_in,
                              void* d_out, int out_size, void* d_ws, size_t ws_size,
                              hipStream_t stream)
{
  const float* x  = (const float*)d_in[0];
  const float* W1 = (const float*)d_in[1];
  const float* b1 = (const float*)d_in[2];
  const float* W2 = (const float*)d_in[3];
  const float* b2 = (const float*)d_in[4];
  const float* W3 = (const float*)d_in[5];
  const float* b3 = (const float*)d_in[6];
  const float* CM = (const float*)d_in[7];

  float* out  = (float*)d_out;            // [8][5120]
  float* feat = out + B8 * NOUT;          // [8][1024]

  float* ws      = (float*)d_ws;
  float* parts1  = ws;                      // [ 8][8][2048] = 131072 f
  float* parts2  = parts1 + 8  * 8 * NH1;   // [16][8][1024] = 131072 f
  float* parts3  = parts2 + 16 * 8 * NH2;   // [ 4][8][5120] = 163840 f
  float* logits  = parts3 + 4  * 8 * NOUT;  // [8][5120]     =  40960 f
  float* tpart   = logits + 8 * NOUT;       // [5][8][5120]  = 204800 f

  // h1 partials: x[8,1024] @ W1[1024,2048], K split 8 -> 256 blocks
  gemm8<DIN, NH1, 8, 0, false, false><<<256, 256, 0, stream>>>(x, nullptr, W1, parts1, nullptr);
  // h2 partials: relu(sum parts1 + b1) @ W2[2048,1024], K split 16 -> 256 blocks
  gemm8<NH1, NH2, 16, 8, true, false><<<256, 256, 0, stream>>>(parts1, b1, W2, parts2, nullptr);
  // logits partials: relu(sum parts2 + b2) @ W3[1024,5120], K split 4 -> 320 blocks
  // (staged A == features; written by cb==0 blocks)
  gemm8<NH2, NOUT, 4, 16, true, true><<<320, 256, 0, stream>>>(parts2, b2, W3, parts3, feat);
  // logits = sum parts3 + b3
  finalize_logits<<<40, 256, 0, stream>>>(parts3, b3, logits);
  // tropical: logits-in-registers, 16 rows/wave, grid (80 x 5) x 4 waves
  {
    dim3 grid(80, TKS);
    tropical_reg<<<grid, 256, 0, stream>>>(logits, CM, tpart);
  }
  // fold k-chunks
  tropical_combine<<<40, 256, 0, stream>>>(tpart, out);
}

// Round 13
// 61.549 us; speedup vs baseline: 1.1182x; 1.1182x over previous
//
#include <hip/hip_runtime.h>
#include <cstdint>

#define B8   8
#define DIN  1024
#define NH1  2048
#define NH2  1024
#define NOUT 5120
#define TKS  5      // tropical k-split (5120 = 5 * 1024)

__device__ __forceinline__ float4 ld4(const float* p) {
  return *reinterpret_cast<const float4*>(p);
}
__device__ __forceinline__ void st4(float* p, float4 v) {
  *reinterpret_cast<float4*>(p) = v;
}

// C_parts[kb][8][N] = A[8, k0:k0+KC] @ W[k0:k0+KC, :]   (partial over K-chunk)
// A source: raw input (NPART==0) or sum of NPART partials + bias (+ReLU).
// The staged (finalized) A chunk is optionally written out (features).
template<int K, int N, int KSPLIT, int NPART, bool RELU_IN, bool WRITE_STAGE>
__global__ __launch_bounds__(256)
void gemm8(const float* __restrict__ Asrc, const float* __restrict__ bias_in,
           const float* __restrict__ W, float* __restrict__ Cparts,
           float* __restrict__ stage_out)
{
  constexpr int KC    = K / KSPLIT;   // k-chunk per block
  constexpr int KC4   = KC / 4;
  constexpr int NCOLB = N / 64;       // 64 output cols per block
  constexpr int KT    = KC / 16;      // k elements per thread

  __shared__ float A_lds[8][KC];      // <= 8 KB
  __shared__ float red[16][8][64];    // 32 KB

  const int tid = threadIdx.x;
  const int kb  = blockIdx.x / NCOLB;
  const int cb  = blockIdx.x % NCOLB;
  const int k0  = kb * KC;

  // ---- stage A chunk into LDS (finalize previous stage: sum partials + bias + relu)
  for (int e = tid; e < 8 * KC4; e += 256) {
    const int b = e / KC4, k4 = e - b * KC4;
    float4 v;
    if constexpr (NPART == 0) {
      v = ld4(&Asrc[(size_t)b * K + k0 + 4 * k4]);
    } else {
      v = ld4(&bias_in[k0 + 4 * k4]);
      #pragma unroll
      for (int p = 0; p < NPART; ++p) {
        float4 t = ld4(&Asrc[((size_t)p * 8 + b) * K + k0 + 4 * k4]);
        v.x += t.x; v.y += t.y; v.z += t.z; v.w += t.w;
      }
      if constexpr (RELU_IN) {
        v.x = fmaxf(v.x, 0.f); v.y = fmaxf(v.y, 0.f);
        v.z = fmaxf(v.z, 0.f); v.w = fmaxf(v.w, 0.f);
      }
    }
    st4(&A_lds[b][4 * k4], v);
    if constexpr (WRITE_STAGE) {
      if (cb == 0) st4(&stage_out[(size_t)b * K + k0 + 4 * k4], v);
    }
  }
  __syncthreads();

  // ---- main loop: 16 col-groups (float4) x 16 k-slices
  const int g  = tid & 15, ks = tid >> 4;
  const int c0 = cb * 64 + g * 4;
  float4 acc[8];
  #pragma unroll
  for (int b = 0; b < 8; ++b) acc[b] = make_float4(0.f, 0.f, 0.f, 0.f);

  const float* Wp = &W[(size_t)(k0 + ks * KT) * N + c0];
  #pragma unroll
  for (int i = 0; i < KT; i += 4) {
    const float4 w0 = ld4(Wp + (size_t)(i + 0) * N);
    const float4 w1 = ld4(Wp + (size_t)(i + 1) * N);
    const float4 w2 = ld4(Wp + (size_t)(i + 2) * N);
    const float4 w3 = ld4(Wp + (size_t)(i + 3) * N);
    const int kk = ks * KT + i;
    #pragma unroll
    for (int b = 0; b < 8; ++b) {
      const float4 a = ld4(&A_lds[b][kk]);   // broadcast within 16-lane group
      acc[b].x += a.x * w0.x + a.y * w1.x + a.z * w2.x + a.w * w3.x;
      acc[b].y += a.x * w0.y + a.y * w1.y + a.z * w2.y + a.w * w3.y;
      acc[b].z += a.x * w0.z + a.y * w1.z + a.z * w2.z + a.w * w3.z;
      acc[b].w += a.x * w0.w + a.y * w1.w + a.z * w2.w + a.w * w3.w;
    }
  }

  // ---- reduce the 16 k-slices through LDS
  __syncthreads();
  #pragma unroll
  for (int b = 0; b < 8; ++b) st4(&red[ks][b][g * 4], acc[b]);
  __syncthreads();

  for (int p = tid; p < 512; p += 256) {
    const int c = p & 63, b = p >> 6;
    float s = 0.f;
    #pragma unroll
    for (int j = 0; j < 16; ++j) s += red[j][b][c];
    Cparts[((size_t)kb * 8 + b) * N + cb * 64 + c] = s;
  }
}

// logits[8][5120] = sum of 4 partials + b3
__global__ __launch_bounds__(256)
void finalize_logits(const float* __restrict__ parts, const float* __restrict__ b3,
                     float* __restrict__ logits)
{
  const int i  = blockIdx.x * 256 + threadIdx.x;   // 10240 float4s, grid exact
  const int b  = i / 1280, k4 = i - b * 1280;
  float4 v = ld4(&b3[4 * k4]);
  #pragma unroll
  for (int p = 0; p < 4; ++p) {
    const float4 t = ld4(&parts[((size_t)p * 8 + b) * NOUT + 4 * k4]);
    v.x += t.x; v.y += t.y; v.z += t.z; v.w += t.w;
  }
  st4(&logits[(size_t)b * NOUT + 4 * k4], v);
}

// tpart[ks][b][o] = max_{k in chunk ks} logits[b][k] * CM[o][k]
// LDS-RESIDENT LOGITS, OCCUPANCY AT THE LDS CAP (R11 structure, index fix):
// stage [8][1024] logits ONCE per block into 32 KB LDS (one barrier per
// block lifetime); ds_read traffic bypasses the L1/L2 ingest path that
// capped R0-R10. Global traffic = the compulsory 105 MB CM stream only.
// Grid 320x5 = 1600 blocks -> 5 blocks/CU (LDS cap) = 20 waves/CU TLP.
// 4 waves x 4 rows; per row: 4 hoisted CM loads + 32 ds_read_b128 +
// 256 VALU. Lane l covers k = 4*l + 256*j, j=0..3 (offsets +256 FLOATS,
// not +1024 -- the R11 bug).
__global__ __launch_bounds__(256)
void tropical_lds(const float* __restrict__ logits, const float* __restrict__ CM,
                  float* __restrict__ tpart)
{
  __shared__ float LgL[8][1024];   // 32 KB logits chunk

  const int tid = threadIdx.x;
  const int w   = tid >> 6;      // wave 0..3
  const int l   = tid & 63;      // lane
  const int ks  = blockIdx.y;    // k-chunk 0..4
  const int k0  = ks * 1024;
  const int o0w = blockIdx.x * 16 + w * 4;   // wave's 4 rows

  // ---- stage logits chunk ONCE (2048 float4s over 256 threads, coalesced)
  #pragma unroll
  for (int it = 0; it < 8; ++it) {
    const int e = tid + 256 * it;
    const int b = e >> 8, k4 = e & 255;
    st4(&LgL[b][4 * k4], ld4(&logits[(size_t)b * NOUT + k0 + 4 * k4]));
  }
  __syncthreads();   // the only barrier in the block's lifetime

  float* tp = &tpart[(size_t)ks * 8 * NOUT];

  for (int r = 0; r < 4; ++r) {          // wave's 4 CM rows
    const float* cmr = &CM[(size_t)(o0w + r) * NOUT + k0 + 4 * l];
    // hoist the row's 4 coalesced CM loads (independent, in flight together)
    float4 c0 = ld4(cmr);
    float4 c1 = ld4(cmr + 256);
    float4 c2 = ld4(cmr + 512);
    float4 c3 = ld4(cmr + 768);

    float pm[8];
    #pragma unroll
    for (int b = 0; b < 8; ++b) pm[b] = -3.402823466e38f;

    #pragma unroll
    for (int b = 0; b < 8; ++b) {
      const float4 v0 = ld4(&LgL[b][4 * l]);
      const float4 v1 = ld4(&LgL[b][4 * l + 256]);
      const float4 v2 = ld4(&LgL[b][4 * l + 512]);
      const float4 v3 = ld4(&LgL[b][4 * l + 768]);
      float m0, m1;
      m0 = fmaxf(v0.x * c0.x, v0.y * c0.y);
      m1 = fmaxf(v0.z * c0.z, v0.w * c0.w);
      pm[b] = fmaxf(pm[b], fmaxf(m0, m1));
      m0 = fmaxf(v1.x * c1.x, v1.y * c1.y);
      m1 = fmaxf(v1.z * c1.z, v1.w * c1.w);
      pm[b] = fmaxf(pm[b], fmaxf(m0, m1));
      m0 = fmaxf(v2.x * c2.x, v2.y * c2.y);
      m1 = fmaxf(v2.z * c2.z, v2.w * c2.w);
      pm[b] = fmaxf(pm[b], fmaxf(m0, m1));
      m0 = fmaxf(v3.x * c3.x, v3.y * c3.y);
      m1 = fmaxf(v3.z * c3.z, v3.w * c3.w);
      pm[b] = fmaxf(pm[b], fmaxf(m0, m1));
    }

    // cross-lane max reduce; lane 0 writes tpart[ks][b][row]
    #pragma unroll
    for (int b = 0; b < 8; ++b) {
      float v = pm[b];
      for (int m = 32; m; m >>= 1) v = fmaxf(v, __shfl_xor(v, m));
      if (l == 0) tp[(size_t)b * NOUT + o0w + r] = v;
    }
  }
}

// out[b][o] = max_ks tpart[ks][b][o]
__global__ __launch_bounds__(256)
void tropical_combine(const float* __restrict__ tpart, float* __restrict__ out)
{
  const int i = blockIdx.x * 256 + threadIdx.x;   // 10240 float4s, grid exact
  float4 v = ld4(&tpart[4 * (size_t)i]);
  #pragma unroll
  for (int p = 1; p < TKS; ++p) {
    const float4 t = ld4(&tpart[(size_t)p * 8 * NOUT + 4 * (size_t)i]);
    v.x = fmaxf(v.x, t.x); v.y = fmaxf(v.y, t.y);
    v.z = fmaxf(v.z, t.z); v.w = fmaxf(v.w, t.w);
  }
  st4(&out[4 * (size_t)i], v);
}

extern "C" void kernel_launch(void* const* d_in, const int* in_sizes, int n_in,
                              void* d_out, int out_size, void* d_ws, size_t ws_size,
                              hipStream_t stream)
{
  const float* x  = (const float*)d_in[0];
  const float* W1 = (const float*)d_in[1];
  const float* b1 = (const float*)d_in[2];
  const float* W2 = (const float*)d_in[3];
  const float* b2 = (const float*)d_in[4];
  const float* W3 = (const float*)d_in[5];
  const float* b3 = (const float*)d_in[6];
  const float* CM = (const float*)d_in[7];

  float* out  = (float*)d_out;            // [8][5120]
  float* feat = out + B8 * NOUT;          // [8][1024]

  float* ws      = (float*)d_ws;
  float* parts1  = ws;                      // [ 8][8][2048] = 131072 f
  float* parts2  = parts1 + 8  * 8 * NH1;   // [16][8][1024] = 131072 f
  float* parts3  = parts2 + 16 * 8 * NH2;   // [ 4][8][5120] = 163840 f
  float* logits  = parts3 + 4  * 8 * NOUT;  // [8][5120]     =  40960 f
  float* tpart   = logits + 8 * NOUT;       // [5][8][5120]  = 204800 f

  // h1 partials: x[8,1024] @ W1[1024,2048], K split 8 -> 256 blocks
  gemm8<DIN, NH1, 8, 0, false, false><<<256, 256, 0, stream>>>(x, nullptr, W1, parts1, nullptr);
  // h2 partials: relu(sum parts1 + b1) @ W2[2048,1024], K split 16 -> 256 blocks
  gemm8<NH1, NH2, 16, 8, true, false><<<256, 256, 0, stream>>>(parts1, b1, W2, parts2, nullptr);
  // logits partials: relu(sum parts2 + b2) @ W3[1024,5120], K split 4 -> 320 blocks
  // (staged A == features; written by cb==0 blocks)
  gemm8<NH2, NOUT, 4, 16, true, true><<<320, 256, 0, stream>>>(parts2, b2, W3, parts3, feat);
  // logits = sum parts3 + b3
  finalize_logits<<<40, 256, 0, stream>>>(parts3, b3, logits);
  // tropical: 320 row-groups x 5 k-chunks, LDS-resident logits, 20 waves/CU
  {
    dim3 grid(320, TKS);
    tropical_lds<<<grid, 256, 0, stream>>>(logits, CM, tpart);
  }
  // fold k-chunks
  tropical_combine<<<40, 256, 0, stream>>>(tpart, out);
}